// Round 3
// baseline (385.752 us; speedup 1.0000x reference)
//
#include <hip/hip_runtime.h>
#include <cstdint>
#include <cstddef>

#define N_NODES 8192
#define F_OUT   64
#define DINT    32
#define ALPHA   0.2f

// ---------------------------------------------------------------------------
// K1: h = x @ W, fused s,t projections. One wave per row.
// ---------------------------------------------------------------------------
__global__ __launch_bounds__(64) void k_h_st(
    const float* __restrict__ x, const float* __restrict__ ie,
    const float* __restrict__ W, const float* __restrict__ a,
    float* __restrict__ h, float* __restrict__ s, float* __restrict__ t)
{
    const int i = blockIdx.x;
    const int f = threadIdx.x;              // 0..63
    const float* xr = x + (size_t)i * 64;

    float acc = 0.f;
    #pragma unroll 16
    for (int k = 0; k < 64; ++k)
        acc = fmaf(xr[k], W[k * 64 + f], acc);

    h[(size_t)i * 64 + f] = acc;

    float ps = acc * a[f];
    float pt = acc * a[64 + f];
    if (f < DINT) {
        float e = ie[(size_t)i * DINT + f];
        ps = fmaf(e, a[128 + f], ps);
        pt = fmaf(e, a[160 + f], pt);
    }
    #pragma unroll
    for (int m = 1; m < 64; m <<= 1) {
        ps += __shfl_xor(ps, m, 64);
        pt += __shfl_xor(pt, m, 64);
    }
    if (f == 0) { s[i] = ps; t[i] = pt; }
}

// ---------------------------------------------------------------------------
// K2: rank/count via brute-force counting, LDS-staged, float4 compares.
// Block = 4 waves = 4 indices; blockIdx.y = which.
//  which==0 (idx=i): pos[i]=#{j: t_j < -s_i}; smax computed in-wave for free
//                    (every wave scans all of s); scatters e^{s_i-smax},
//                    e^{a(s_i-smax)} into s-sorted slot rank_s(i).
//  which==1 (idx=j): scatters inv_t[rank]=j, t_sorted[rank]=t_j,
//                    q_sorted[rank]=#{i: s_i < -t_j}.
// Strict rank with index tie-break => exact permutation.
// ---------------------------------------------------------------------------
__global__ __launch_bounds__(256) void k_ranks(
    const float* __restrict__ s, const float* __restrict__ t,
    float* __restrict__ smax,
    int* __restrict__ pos, int* __restrict__ inv_t,
    float* __restrict__ t_sorted, int* __restrict__ q_sorted,
    float* __restrict__ se1, float* __restrict__ se2)
{
    __shared__ __align__(16) float s_sh[2048];
    __shared__ __align__(16) float t_sh[2048];
    const int wave = threadIdx.x >> 6, lane = threadIdx.x & 63;
    const int idx = blockIdx.x * 4 + wave;      // 0..8191
    const int which = blockIdx.y;

    const float key = (which == 0) ? s[idx] : t[idx];
    const float nkey = -key;
    int c1 = 0, c2 = 0;
    float m = -1e30f;

    for (int c = 0; c < 4; ++c) {
        const int base = c * 2048;
        #pragma unroll
        for (int l = 0; l < 2; ++l) {
            int o = threadIdx.x * 4 + l * 1024;
            *reinterpret_cast<float4*>(&s_sh[o]) =
                *reinterpret_cast<const float4*>(&s[base + o]);
            *reinterpret_cast<float4*>(&t_sh[o]) =
                *reinterpret_cast<const float4*>(&t[base + o]);
        }
        __syncthreads();

        if (which == 0) {
            for (int k = lane * 4; k < 2048; k += 256) {
                float4 sv = *reinterpret_cast<const float4*>(&s_sh[k]);
                float4 tv = *reinterpret_cast<const float4*>(&t_sh[k]);
                const int k0 = base + k;
                c1 += (sv.x < key) || (sv.x == key && (k0 + 0) < idx);
                c1 += (sv.y < key) || (sv.y == key && (k0 + 1) < idx);
                c1 += (sv.z < key) || (sv.z == key && (k0 + 2) < idx);
                c1 += (sv.w < key) || (sv.w == key && (k0 + 3) < idx);
                c2 += (tv.x < nkey) + (tv.y < nkey) + (tv.z < nkey) + (tv.w < nkey);
                m = fmaxf(m, fmaxf(fmaxf(sv.x, sv.y), fmaxf(sv.z, sv.w)));
            }
        } else {
            for (int k = lane * 4; k < 2048; k += 256) {
                float4 tv = *reinterpret_cast<const float4*>(&t_sh[k]);
                float4 sv = *reinterpret_cast<const float4*>(&s_sh[k]);
                const int k0 = base + k;
                c1 += (tv.x < key) || (tv.x == key && (k0 + 0) < idx);
                c1 += (tv.y < key) || (tv.y == key && (k0 + 1) < idx);
                c1 += (tv.z < key) || (tv.z == key && (k0 + 2) < idx);
                c1 += (tv.w < key) || (tv.w == key && (k0 + 3) < idx);
                c2 += (sv.x < nkey) + (sv.y < nkey) + (sv.z < nkey) + (sv.w < nkey);
            }
        }
        __syncthreads();
    }

    int p = c1 * 16384 + c2;                    // c2 <= 8192 < 16384: no carry
    #pragma unroll
    for (int mm = 1; mm < 64; mm <<= 1) p += __shfl_xor(p, mm, 64);

    if (which == 0) {
        #pragma unroll
        for (int mm = 1; mm < 64; mm <<= 1) m = fmaxf(m, __shfl_xor(m, mm, 64));
        if (lane == 0) {
            const int r1 = p >> 14, r2 = p & 16383;
            pos[idx] = r2;
            const float d = key - m;            // s_i - smax (exact, order-free)
            se1[r1] = __expf(d);
            se2[r1] = __expf(ALPHA * d);
            if (idx == 0) smax[0] = m;
        }
    } else if (lane == 0) {
        const int r1 = p >> 14, r2 = p & 16383;
        inv_t[r1] = idx;
        t_sorted[r1] = key;
        q_sorted[r1] = r2;
    }
}

// ---------------------------------------------------------------------------
// K3 (single block, 1024 thr): fp64 scalar scans + per-column coefficients.
//  Phase A: SufP1[k]=sum_{k'>=k} se1[k'] (SufP1[8192]=0);
//           PreP2[k]=sum_{k'<k} se2[k'] (PreP2[8192]=total).
//  Phase B (sorted order r): D = E1*SufP1[q] + E2*PreP2[q] >= 1;
//           cf1[r]=E1/D, cf2[r]=E2/D.
// ---------------------------------------------------------------------------
__global__ __launch_bounds__(1024) void k_mid(
    const float* __restrict__ se1, const float* __restrict__ se2,
    const float* __restrict__ smax_p,
    const float* __restrict__ t_sorted, const int* __restrict__ q_sorted,
    float* __restrict__ SufP1, float* __restrict__ PreP2,
    float* __restrict__ cf1, float* __restrict__ cf2)
{
    __shared__ double sc[1024];
    const int tid = threadIdx.x;
    double loc[8], sum;

    // PreP2 (exclusive prefix of se2)
    sum = 0.0;
    #pragma unroll
    for (int k = 0; k < 8; ++k) { loc[k] = (double)se2[tid * 8 + k]; sum += loc[k]; }
    sc[tid] = sum; __syncthreads();
    for (int off = 1; off < 1024; off <<= 1) {
        double v = (tid >= off) ? sc[tid - off] : 0.0;
        __syncthreads();
        sc[tid] += v;
        __syncthreads();
    }
    {
        double run = sc[tid] - sum;
        #pragma unroll
        for (int k = 0; k < 8; ++k) { PreP2[tid * 8 + k] = (float)run; run += loc[k]; }
        if (tid == 1023) PreP2[8192] = (float)run;
    }
    __syncthreads();

    // SufP1 (inclusive suffix of se1)
    sum = 0.0;
    #pragma unroll
    for (int k = 0; k < 8; ++k) { loc[k] = (double)se1[tid * 8 + k]; sum += loc[k]; }
    sc[tid] = sum; __syncthreads();
    for (int off = 1; off < 1024; off <<= 1) {
        double v = (tid >= off) ? sc[tid - off] : 0.0;
        __syncthreads();
        sc[tid] += v;
        __syncthreads();
    }
    {
        double acc = sc[1023] - sc[tid];
        #pragma unroll
        for (int k = 7; k >= 0; --k) { acc += loc[k]; SufP1[tid * 8 + k] = (float)acc; }
        if (tid == 1023) SufP1[8192] = 0.f;
    }

    __threadfence();
    __syncthreads();

    // Phase B: coefficients in sorted order (fully coalesced)
    const float smax = smax_p[0];
    #pragma unroll
    for (int k = 0; k < 8; ++k) {
        const int r = tid + k * 1024;
        const float tj = t_sorted[r];
        const float zc = smax + tj;
        const float c = fmaxf(zc, ALPHA * zc);     // lrelu(smax+t_j) = col max
        const float E1 = __expf(zc - c);
        const float E2 = __expf(ALPHA * zc - c);
        const int qj = q_sorted[r];
        const float D = E1 * SufP1[qj] + E2 * PreP2[qj];
        const float invD = 1.f / D;
        cf1[r] = E1 * invD;
        cf2[r] = E2 * invD;
    }
}

// ---------------------------------------------------------------------------
// K4: per-tile (128 sorted rows) column sums of cf1*h and cf2*h (gathered).
// ---------------------------------------------------------------------------
__global__ __launch_bounds__(256) void k_tilesum(
    const float* __restrict__ h, const int* __restrict__ inv_t,
    const float* __restrict__ cf1, const float* __restrict__ cf2,
    float* __restrict__ T1, float* __restrict__ T2)
{
    const int tile = blockIdx.x;                 // 0..63
    const int wave = threadIdx.x >> 6, f = threadIdx.x & 63;
    const int r0 = tile * 128 + wave * 32;
    float a1 = 0.f, a2 = 0.f;
    for (int k = 0; k < 32; ++k) {
        const int r = r0 + k;
        const int j = inv_t[r];
        const float v = h[(size_t)j * 64 + f];
        a1 = fmaf(cf1[r], v, a1);
        a2 = fmaf(cf2[r], v, a2);
    }
    __shared__ float red[2][4][64];
    red[0][wave][f] = a1; red[1][wave][f] = a2;
    __syncthreads();
    if (wave == 0)
        T1[tile * 64 + f] = red[0][0][f] + red[0][1][f] + red[0][2][f] + red[0][3][f];
    else if (wave == 1)
        T2[tile * 64 + f] = red[1][0][f] + red[1][1][f] + red[1][2][f] + red[1][3][f];
}

// ---------------------------------------------------------------------------
// K5: final scans with inline tile offsets (no separate tilescan kernel).
//  arr==0: S1[r] = inclusive suffix of cf1*h rows;  S1[8192]=0
//  arr==1: S2[r] = exclusive prefix  of cf2*h rows; S2[8192]=total
// 8-row batched gathers keep L2 latency off the acc chain.
// ---------------------------------------------------------------------------
__global__ __launch_bounds__(64) void k_scan2(
    const float* __restrict__ h, const int* __restrict__ inv_t,
    const float* __restrict__ cf1, const float* __restrict__ cf2,
    const float* __restrict__ T1, const float* __restrict__ T2,
    float* __restrict__ S1, float* __restrict__ S2)
{
    const int tile = blockIdx.x, arr = blockIdx.y, f = threadIdx.x;
    if (arr == 0) {
        float acc = 0.f;
        for (int tt = tile + 1; tt < 64; ++tt) acc += T1[tt * 64 + f];
        if (tile == 63) S1[(size_t)8192 * 64 + f] = 0.f;
        for (int rb = 15; rb >= 0; --rb) {
            const int r0 = tile * 128 + rb * 8;
            float v[8];
            #pragma unroll
            for (int k = 0; k < 8; ++k)
                v[k] = cf1[r0 + k] * h[(size_t)inv_t[r0 + k] * 64 + f];
            #pragma unroll
            for (int k = 7; k >= 0; --k) { acc += v[k]; S1[(size_t)(r0 + k) * 64 + f] = acc; }
        }
    } else {
        float acc = 0.f;
        for (int tt = 0; tt < tile; ++tt) acc += T2[tt * 64 + f];
        for (int rb = 0; rb < 16; ++rb) {
            const int r0 = tile * 128 + rb * 8;
            float v[8];
            #pragma unroll
            for (int k = 0; k < 8; ++k)
                v[k] = cf2[r0 + k] * h[(size_t)inv_t[r0 + k] * 64 + f];
            #pragma unroll
            for (int k = 0; k < 8; ++k) { S2[(size_t)(r0 + k) * 64 + f] = acc; acc += v[k]; }
        }
        if (tile == 63) S2[(size_t)8192 * 64 + f] = acc;
    }
}

// ---------------------------------------------------------------------------
// K6: out[i,f] = elu( e^{s_i-smax}*S1[pos_i][f] + e^{a(s_i-smax)}*S2[pos_i][f] )
// ---------------------------------------------------------------------------
__global__ __launch_bounds__(256) void k_out(
    const float* __restrict__ s, const float* __restrict__ smax_p,
    const int* __restrict__ pos,
    const float* __restrict__ S1, const float* __restrict__ S2,
    float* __restrict__ out)
{
    const int i = blockIdx.x * 4 + (threadIdx.x >> 6);
    const int f = threadIdx.x & 63;
    const float d = s[i] - smax_p[0];
    const float e1 = __expf(d), e2 = __expf(ALPHA * d);
    const int p = pos[i];
    const float v = fmaf(e1, S1[(size_t)p * 64 + f], e2 * S2[(size_t)p * 64 + f]);
    out[(size_t)i * 64 + f] = v > 0.f ? v : expm1f(v);
}

// ---------------------------------------------------------------------------
extern "C" void kernel_launch(void* const* d_in, const int* in_sizes, int n_in,
                              void* d_out, int out_size, void* d_ws, size_t ws_size,
                              hipStream_t stream)
{
    // dict order: input, adj (unused by reference), intent_embeds, W, a
    const float* x  = (const float*)d_in[0];
    const float* ie = (const float*)d_in[2];
    const float* W  = (const float*)d_in[3];
    const float* a  = (const float*)d_in[4];
    float* out = (float*)d_out;

    float* p = (float*)d_ws;
    float* h        = p; p += (size_t)N_NODES * F_OUT;
    float* s        = p; p += N_NODES;
    float* t        = p; p += N_NODES;
    float* smax     = p; p += 16;
    float* se1      = p; p += N_NODES;
    float* se2      = p; p += N_NODES;
    float* SufP1    = p; p += N_NODES + 64;            // 8193 used
    float* PreP2    = p; p += N_NODES + 64;
    float* t_sorted = p; p += N_NODES;
    float* cf1      = p; p += N_NODES;
    float* cf2      = p; p += N_NODES;
    float* T1       = p; p += 64 * 64;
    float* T2       = p; p += 64 * 64;
    float* S1       = p; p += (size_t)(N_NODES + 1) * F_OUT + 64;  // 8193 rows
    float* S2       = p; p += (size_t)(N_NODES + 1) * F_OUT + 64;
    int* pos        = (int*)p; p += N_NODES;
    int* inv_t      = (int*)p; p += N_NODES;
    int* q_sorted   = (int*)p; p += N_NODES;
    // ~7 MB total, far under ws_size

    k_h_st    <<<N_NODES, 64, 0, stream>>>(x, ie, W, a, h, s, t);
    k_ranks   <<<dim3(N_NODES / 4, 2), 256, 0, stream>>>(s, t, smax,
                      pos, inv_t, t_sorted, q_sorted, se1, se2);
    k_mid     <<<1, 1024, 0, stream>>>(se1, se2, smax, t_sorted, q_sorted,
                      SufP1, PreP2, cf1, cf2);
    k_tilesum <<<64, 256, 0, stream>>>(h, inv_t, cf1, cf2, T1, T2);
    k_scan2   <<<dim3(64, 2), 64, 0, stream>>>(h, inv_t, cf1, cf2, T1, T2, S1, S2);
    k_out     <<<N_NODES / 4, 256, 0, stream>>>(s, smax, pos, S1, S2, out);
}

// Round 4
// 362.486 us; speedup vs baseline: 1.0642x; 1.0642x over previous
//
#include <hip/hip_runtime.h>
#include <cstdint>
#include <cstddef>

#define N_NODES 8192
#define F_OUT   64
#define DINT    32
#define ALPHA   0.2f

// ---------------------------------------------------------------------------
// K1: h = x @ W, fused s,t projections. One wave per row.
// ---------------------------------------------------------------------------
__global__ __launch_bounds__(64) void k_h_st(
    const float* __restrict__ x, const float* __restrict__ ie,
    const float* __restrict__ W, const float* __restrict__ a,
    float* __restrict__ h, float* __restrict__ s, float* __restrict__ t)
{
    const int i = blockIdx.x;
    const int f = threadIdx.x;              // 0..63
    const float* xr = x + (size_t)i * 64;

    float acc = 0.f;
    #pragma unroll 16
    for (int k = 0; k < 64; ++k)
        acc = fmaf(xr[k], W[k * 64 + f], acc);

    h[(size_t)i * 64 + f] = acc;

    float ps = acc * a[f];
    float pt = acc * a[64 + f];
    if (f < DINT) {
        float e = ie[(size_t)i * DINT + f];
        ps = fmaf(e, a[128 + f], ps);
        pt = fmaf(e, a[160 + f], pt);
    }
    #pragma unroll
    for (int m = 1; m < 64; m <<= 1) {
        ps += __shfl_xor(ps, m, 64);
        pt += __shfl_xor(pt, m, 64);
    }
    if (f == 0) { s[i] = ps; t[i] = pt; }
}

// ---------------------------------------------------------------------------
// K2: ranks/counts. 8 keys per wave, 4 waves/block => 32 keys/block.
// Elements staged in LDS as packed u64 = (sortable_int(value)<<32)|index
// (strict total order: value, then index) plus the OTHER array as float.
//  which==0 (keys=s): rank_s -> scatter se1/se2; pos[i]=#{j: t_j < -s_i};
//                     wave u64-max of s gives smax for free.
//  which==1 (keys=t): inv_t[rank]=j, t_sorted[rank]=t_j, q[rank]=#{i: s_i<-t_j}.
// ---------------------------------------------------------------------------
__global__ __launch_bounds__(256) void k_ranks(
    const float* __restrict__ s, const float* __restrict__ t,
    float* __restrict__ smax,
    int* __restrict__ pos, int* __restrict__ inv_t,
    float* __restrict__ t_sorted, int* __restrict__ q_sorted,
    float* __restrict__ se1, float* __restrict__ se2)
{
    __shared__ __align__(16) unsigned long long u_sh[2048];
    __shared__ __align__(16) float f_sh[2048];
    const int wave = threadIdx.x >> 6, lane = threadIdx.x & 63;
    const int which = blockIdx.y;
    const int key0 = blockIdx.x * 32 + wave * 8;

    const float* __restrict__ karr = (which == 0) ? s : t;  // c1/rank array
    const float* __restrict__ oarr = (which == 0) ? t : s;  // c2/count array

    float kf[8], nk[8];
    unsigned long long ku[8];
    #pragma unroll
    for (int l = 0; l < 8; ++l) {
        kf[l] = karr[key0 + l];
        unsigned int b = __float_as_uint(kf[l]);
        b = (b & 0x80000000u) ? ~b : (b | 0x80000000u);
        ku[l] = ((unsigned long long)b << 32) | (unsigned int)(key0 + l);
        nk[l] = -kf[l];
    }

    int c1[8] = {0,0,0,0,0,0,0,0}, c2[8] = {0,0,0,0,0,0,0,0};
    unsigned long long mx = 0ull;

    for (int c = 0; c < 4; ++c) {
        const int base = c * 2048;
        {   // stage: each thread packs 8 consecutive elements
            const int e0 = threadIdx.x * 8;
            float4 a0 = *reinterpret_cast<const float4*>(&karr[base + e0]);
            float4 a1 = *reinterpret_cast<const float4*>(&karr[base + e0 + 4]);
            float4 b0 = *reinterpret_cast<const float4*>(&oarr[base + e0]);
            float4 b1 = *reinterpret_cast<const float4*>(&oarr[base + e0 + 4]);
            const float av[8] = {a0.x,a0.y,a0.z,a0.w,a1.x,a1.y,a1.z,a1.w};
            #pragma unroll
            for (int e = 0; e < 8; ++e) {
                unsigned int b = __float_as_uint(av[e]);
                b = (b & 0x80000000u) ? ~b : (b | 0x80000000u);
                u_sh[e0 + e] = ((unsigned long long)b << 32)
                             | (unsigned int)(base + e0 + e);
            }
            *reinterpret_cast<float4*>(&f_sh[e0])     = b0;
            *reinterpret_cast<float4*>(&f_sh[e0 + 4]) = b1;
        }
        __syncthreads();

        for (int k = lane * 4; k < 2048; k += 256) {
            const ulonglong2 p0 = *reinterpret_cast<const ulonglong2*>(&u_sh[k]);
            const ulonglong2 p1 = *reinterpret_cast<const ulonglong2*>(&u_sh[k + 2]);
            const float4 fv = *reinterpret_cast<const float4*>(&f_sh[k]);
            if (which == 0) {
                unsigned long long m01 = p0.x > p0.y ? p0.x : p0.y;
                unsigned long long m23 = p1.x > p1.y ? p1.x : p1.y;
                unsigned long long m03 = m01 > m23 ? m01 : m23;
                mx = mx > m03 ? mx : m03;
            }
            #pragma unroll
            for (int l = 0; l < 8; ++l) {
                c1[l] += (int)(p0.x < ku[l]) + (int)(p0.y < ku[l])
                       + (int)(p1.x < ku[l]) + (int)(p1.y < ku[l]);
                c2[l] += (int)(fv.x < nk[l]) + (int)(fv.y < nk[l])
                       + (int)(fv.z < nk[l]) + (int)(fv.w < nk[l]);
            }
        }
        __syncthreads();
    }

    int pk[8];
    #pragma unroll
    for (int l = 0; l < 8; ++l) pk[l] = c1[l] * 16384 + c2[l];
    #pragma unroll
    for (int m = 1; m < 64; m <<= 1) {
        #pragma unroll
        for (int l = 0; l < 8; ++l) pk[l] += __shfl_xor(pk[l], m, 64);
    }

    if (which == 0) {
        #pragma unroll
        for (int m = 1; m < 64; m <<= 1) {
            unsigned long long o = __shfl_xor(mx, m, 64);
            mx = mx > o ? mx : o;
        }
        if (lane == 0) {
            unsigned int b = (unsigned int)(mx >> 32);      // sortable of max s
            b = (b & 0x80000000u) ? (b ^ 0x80000000u) : ~b; // inverse map
            const float smax_f = __uint_as_float(b);
            if (key0 == 0) smax[0] = smax_f;
            #pragma unroll
            for (int l = 0; l < 8; ++l) {
                const int idx = key0 + l;
                const int r1 = pk[l] >> 14, r2 = pk[l] & 16383;
                pos[idx] = r2;
                const float d = kf[l] - smax_f;
                se1[r1] = __expf(d);
                se2[r1] = __expf(ALPHA * d);
            }
        }
    } else if (lane == 0) {
        #pragma unroll
        for (int l = 0; l < 8; ++l) {
            const int idx = key0 + l;
            const int r1 = pk[l] >> 14, r2 = pk[l] & 16383;
            inv_t[r1] = idx;
            t_sorted[r1] = kf[l];
            q_sorted[r1] = r2;
        }
    }
}

// ---------------------------------------------------------------------------
// K3 (single block, 1024 thr): fp64 scans via wave-shfl (2 barriers), then
// per-column coefficients. SufP1/PreP2 live only in LDS.
//  SufP1[k]=sum_{k'>=k} se1[k'] (SufP1[8192]=0);  PreP2[k]=sum_{k'<k} se2[k'].
//  cf1[r]=E1/D, cf2[r]=E2/D with D = E1*SufP1[q] + E2*PreP2[q]  (>=1).
// ---------------------------------------------------------------------------
__global__ __launch_bounds__(1024) void k_mid(
    const float* __restrict__ se1, const float* __restrict__ se2,
    const float* __restrict__ smax_p,
    const float* __restrict__ t_sorted, const int* __restrict__ q_sorted,
    float* __restrict__ cf1, float* __restrict__ cf2)
{
    __shared__ float suf1[8200];
    __shared__ float pre2[8200];
    __shared__ double wred[2][16];
    const int tid = threadIdx.x, wave = tid >> 6, lane = tid & 63;
    const int base = tid * 8;

    double l1[8], l2[8], s1 = 0.0, s2 = 0.0;
    #pragma unroll
    for (int k = 0; k < 8; ++k) {
        l1[k] = (double)se1[base + k]; s1 += l1[k];
        l2[k] = (double)se2[base + k]; s2 += l2[k];
    }
    double i1 = s1, i2 = s2;                 // wave inclusive scan
    #pragma unroll
    for (int off = 1; off < 64; off <<= 1) {
        double v1 = __shfl_up(i1, off, 64);
        double v2 = __shfl_up(i2, off, 64);
        if (lane >= off) { i1 += v1; i2 += v2; }
    }
    if (lane == 63) { wred[0][wave] = i1; wred[1][wave] = i2; }
    __syncthreads();
    double off1 = 0, off2 = 0, tot1 = 0, tot2 = 0;
    #pragma unroll
    for (int w = 0; w < 16; ++w) {
        const double a = wred[0][w], b = wred[1][w];
        if (w < wave) { off1 += a; off2 += b; }
        tot1 += a; tot2 += b;
    }
    double run1 = off1 + (i1 - s1);          // exclusive prefix at `base`
    double run2 = off2 + (i2 - s2);
    #pragma unroll
    for (int k = 0; k < 8; ++k) {
        suf1[base + k] = (float)(tot1 - run1); run1 += l1[k];
        pre2[base + k] = (float)run2;          run2 += l2[k];
    }
    if (tid == 1023) { suf1[8192] = 0.f; pre2[8192] = (float)tot2; }
    __syncthreads();

    const float smax = smax_p[0];
    #pragma unroll
    for (int k = 0; k < 8; ++k) {
        const int r = tid + k * 1024;
        const float tj = t_sorted[r];
        const float zc = smax + tj;
        const float c = fmaxf(zc, ALPHA * zc);     // lrelu(smax+t_j) = col max
        const float E1 = __expf(zc - c);
        const float E2 = __expf(ALPHA * zc - c);
        const int qj = q_sorted[r];
        const float D = E1 * suf1[qj] + E2 * pre2[qj];
        const float invD = 1.f / D;
        cf1[r] = E1 * invD;
        cf2[r] = E2 * invD;
    }
}

// ---------------------------------------------------------------------------
// K4: per-tile (128 sorted rows) column sums of cf1*h and cf2*h (gathered).
// ---------------------------------------------------------------------------
__global__ __launch_bounds__(256) void k_tilesum(
    const float* __restrict__ h, const int* __restrict__ inv_t,
    const float* __restrict__ cf1, const float* __restrict__ cf2,
    float* __restrict__ T1, float* __restrict__ T2)
{
    const int tile = blockIdx.x;                 // 0..63
    const int wave = threadIdx.x >> 6, f = threadIdx.x & 63;
    const int r0 = tile * 128 + wave * 32;
    float a1 = 0.f, a2 = 0.f;
    for (int k = 0; k < 32; ++k) {
        const int r = r0 + k;
        const int j = inv_t[r];
        const float v = h[(size_t)j * 64 + f];
        a1 = fmaf(cf1[r], v, a1);
        a2 = fmaf(cf2[r], v, a2);
    }
    __shared__ float red[2][4][64];
    red[0][wave][f] = a1; red[1][wave][f] = a2;
    __syncthreads();
    if (wave == 0)
        T1[tile * 64 + f] = red[0][0][f] + red[0][1][f] + red[0][2][f] + red[0][3][f];
    else if (wave == 1)
        T2[tile * 64 + f] = red[1][0][f] + red[1][1][f] + red[1][2][f] + red[1][3][f];
}

// ---------------------------------------------------------------------------
// K5: final scans with inline tile offsets.
//  arr==0: S1[r] = inclusive suffix of cf1*h rows;  S1[8192]=0
//  arr==1: S2[r] = exclusive prefix  of cf2*h rows; S2[8192]=total
// ---------------------------------------------------------------------------
__global__ __launch_bounds__(64) void k_scan2(
    const float* __restrict__ h, const int* __restrict__ inv_t,
    const float* __restrict__ cf1, const float* __restrict__ cf2,
    const float* __restrict__ T1, const float* __restrict__ T2,
    float* __restrict__ S1, float* __restrict__ S2)
{
    const int tile = blockIdx.x, arr = blockIdx.y, f = threadIdx.x;
    if (arr == 0) {
        float acc = 0.f;
        for (int tt = tile + 1; tt < 64; ++tt) acc += T1[tt * 64 + f];
        if (tile == 63) S1[(size_t)8192 * 64 + f] = 0.f;
        for (int rb = 15; rb >= 0; --rb) {
            const int r0 = tile * 128 + rb * 8;
            float v[8];
            #pragma unroll
            for (int k = 0; k < 8; ++k)
                v[k] = cf1[r0 + k] * h[(size_t)inv_t[r0 + k] * 64 + f];
            #pragma unroll
            for (int k = 7; k >= 0; --k) { acc += v[k]; S1[(size_t)(r0 + k) * 64 + f] = acc; }
        }
    } else {
        float acc = 0.f;
        for (int tt = 0; tt < tile; ++tt) acc += T2[tt * 64 + f];
        for (int rb = 0; rb < 16; ++rb) {
            const int r0 = tile * 128 + rb * 8;
            float v[8];
            #pragma unroll
            for (int k = 0; k < 8; ++k)
                v[k] = cf2[r0 + k] * h[(size_t)inv_t[r0 + k] * 64 + f];
            #pragma unroll
            for (int k = 0; k < 8; ++k) { S2[(size_t)(r0 + k) * 64 + f] = acc; acc += v[k]; }
        }
        if (tile == 63) S2[(size_t)8192 * 64 + f] = acc;
    }
}

// ---------------------------------------------------------------------------
// K6: out[i,f] = elu( e^{s_i-smax}*S1[pos_i][f] + e^{a(s_i-smax)}*S2[pos_i][f] )
// ---------------------------------------------------------------------------
__global__ __launch_bounds__(256) void k_out(
    const float* __restrict__ s, const float* __restrict__ smax_p,
    const int* __restrict__ pos,
    const float* __restrict__ S1, const float* __restrict__ S2,
    float* __restrict__ out)
{
    const int i = blockIdx.x * 4 + (threadIdx.x >> 6);
    const int f = threadIdx.x & 63;
    const float d = s[i] - smax_p[0];
    const float e1 = __expf(d), e2 = __expf(ALPHA * d);
    const int p = pos[i];
    const float v = fmaf(e1, S1[(size_t)p * 64 + f], e2 * S2[(size_t)p * 64 + f]);
    out[(size_t)i * 64 + f] = v > 0.f ? v : expm1f(v);
}

// ---------------------------------------------------------------------------
extern "C" void kernel_launch(void* const* d_in, const int* in_sizes, int n_in,
                              void* d_out, int out_size, void* d_ws, size_t ws_size,
                              hipStream_t stream)
{
    // dict order: input, adj (unused by reference), intent_embeds, W, a
    const float* x  = (const float*)d_in[0];
    const float* ie = (const float*)d_in[2];
    const float* W  = (const float*)d_in[3];
    const float* a  = (const float*)d_in[4];
    float* out = (float*)d_out;

    float* p = (float*)d_ws;
    float* h        = p; p += (size_t)N_NODES * F_OUT;
    float* s        = p; p += N_NODES;
    float* t        = p; p += N_NODES;
    float* smax     = p; p += 16;
    float* se1      = p; p += N_NODES;
    float* se2      = p; p += N_NODES;
    float* t_sorted = p; p += N_NODES;
    float* cf1      = p; p += N_NODES;
    float* cf2      = p; p += N_NODES;
    float* T1       = p; p += 64 * 64;
    float* T2       = p; p += 64 * 64;
    float* S1       = p; p += (size_t)(N_NODES + 1) * F_OUT + 64;  // 8193 rows
    float* S2       = p; p += (size_t)(N_NODES + 1) * F_OUT + 64;
    int* pos        = (int*)p; p += N_NODES;
    int* inv_t      = (int*)p; p += N_NODES;
    int* q_sorted   = (int*)p; p += N_NODES;
    // ~7 MB total, far under ws_size

    k_h_st    <<<N_NODES, 64, 0, stream>>>(x, ie, W, a, h, s, t);
    k_ranks   <<<dim3(N_NODES / 32, 2), 256, 0, stream>>>(s, t, smax,
                      pos, inv_t, t_sorted, q_sorted, se1, se2);
    k_mid     <<<1, 1024, 0, stream>>>(se1, se2, smax, t_sorted, q_sorted,
                      cf1, cf2);
    k_tilesum <<<64, 256, 0, stream>>>(h, inv_t, cf1, cf2, T1, T2);
    k_scan2   <<<dim3(64, 2), 64, 0, stream>>>(h, inv_t, cf1, cf2, T1, T2, S1, S2);
    k_out     <<<N_NODES / 4, 256, 0, stream>>>(s, smax, pos, S1, S2, out);
}